// Round 2
// baseline (221.543 us; speedup 1.0000x reference)
//
#include <hip/hip_runtime.h>
#include <hip/hip_fp16.h>

// Trilinear 3D-LUT apply: lut [1,3,33,33,33] f32, x [8,3,1024,1024] f32 in [0,1)
// out [8,3,1024,1024] f32.
//
// V2 strategy on top of the LDS-staged channel split:
//  1) LUT staged as fp16 PAIRS: ls[i] = (lut[i], lut[i+1]) as __half2 (4 B/entry,
//     same 143.7 KB LDS). One dword read yields both b-neighbors -> 4 LDS
//     accesses/pixel instead of 8. With clamped v <= 31.999998 the neighbor
//     offsets are compile-time constants, so the 4 reads (byte offs 0/132/4356/4488
//     from one base) merge into 2x ds_read2_b32. Conflict cycles (address-count
//     driven, random banks) halve; LDS instruction issue drops 4x.
//     Precision: fp16 ulp at |LUT|<~5 gives <=~0.002 output error (interp is a
//     convex combination of corner errors) -- inside the 2^-7 tolerance.
//  2) XCD-aware block swizzle: the 3 channel-blocks of one x-chunk must share an
//     XCD's L2 (they read identical x data). xcd = bid % 8 (round-robin dispatch);
//     give each XCD 32 whole chunks; within an XCD, channel varies fastest so the
//     triple is temporally adjacent. Chunk x-footprint 384 KB << 4 MB L2.
//
// (Round-1 bench failure was a container/infra error; source unchanged in
// substance — resubmitting for measurement.)

#define D   33
#define D2  (33 * 33)
#define D3  (33 * 33 * 33)      // 35937
#define NP  (D3 - 1)            // packed pair entries: 35936 * 4 B = 143,744 B LDS
#define HW  (1024 * 1024)
#define BATCH 8
#define QHW (HW / 4)            // float4 groups per plane
#define NG  (BATCH * QHW)       // float4 groups per channel = 2,097,152
#define CHUNKS 256
#define GPC (NG / CHUNKS)       // groups per chunk = 8192
#define THREADS 1024
#define NXCD 8
#define CPX (CHUNKS / NXCD)     // chunks per XCD = 32

__global__ __launch_bounds__(THREADS) void lut3d_kernel(
    const float* __restrict__ lut, const float* __restrict__ x,
    float* __restrict__ out)
{
    // --- XCD-aware (c, chunk) decode from linear block id -------------------
    // bid % 8 -> XCD (round-robin dispatch assumption; affects locality only).
    // Per XCD: 96 blocks = 32 chunks x 3 channels, channel fastest.
    const int bid = blockIdx.x;
    const int xcd = bid & (NXCD - 1);
    const int s   = bid >> 3;           // 0..95 within this XCD
    const int cl  = s / 3;              // chunk-local 0..31
    const int c   = s - 3 * cl;         // output channel 0..2
    const int chunk = xcd * CPX + cl;

    // --- stage one channel cube as packed fp16 b-pairs ----------------------
    __shared__ __half2 ls[NP];
    {
        const float* lc = lut + c * D3;
        for (int i = threadIdx.x; i < NP; i += THREADS) {
            ls[i] = __halves2half2(__float2half_rn(lc[i]),
                                   __float2half_rn(lc[i + 1]));
        }
    }
    __syncthreads();

    const int tid  = threadIdx.x;
    const int base = chunk * GPC;

    #pragma unroll 1
    for (int it = 0; it < GPC / THREADS; ++it) {
        const int g = base + it * THREADS + tid;       // float4-group id
        const int b = g >> 18;                         // g / QHW (QHW = 2^18)
        const int p = (g & (QHW - 1)) * 4;             // pixel offset in plane

        const float* xb = x + (size_t)b * 3 * HW + p;
        const float4 xr = *(const float4*)(xb);
        const float4 xg = *(const float4*)(xb + HW);
        const float4 xB = *(const float4*)(xb + 2 * HW);

        const float rr[4] = {xr.x, xr.y, xr.z, xr.w};
        const float gg[4] = {xg.x, xg.y, xg.z, xg.w};
        const float bb[4] = {xB.x, xB.y, xB.z, xB.w};
        float oo[4];

        #pragma unroll
        for (int j = 0; j < 4; ++j) {
            // clamp(x,0,1)*32 then cap below 32 so i0<=31 always:
            // makes +1/+33/+1089 neighbor offsets compile-time constants.
            // (at v==32 exactly, f->1 interpolates onto the edge value: same
            // result to ~1e-7.)
            const float vr = fminf(fmaxf(rr[j], 0.f) * 32.f, 31.999998f);
            const float vg = fminf(fmaxf(gg[j], 0.f) * 32.f, 31.999998f);
            const float vb = fminf(fmaxf(bb[j], 0.f) * 32.f, 31.999998f);

            const int r0 = (int)vr, g0 = (int)vg, b0 = (int)vb;  // trunc == floor (v>=0)
            const float fr = vr - (float)r0;
            const float fg = vg - (float)g0;
            const float fb = vb - (float)b0;

            const int idx = __mul24(r0, D2) + __mul24(g0, D) + b0;

            // 4 dword reads at const offsets from one base -> 2x ds_read2_b32.
            // Each __half2 holds (c(b0), c(b0+1)).
            const __half2 h00 = ls[idx];            // (c000, c001)
            const __half2 h01 = ls[idx + D];        // (c010, c011)
            const __half2 h10 = ls[idx + D2];       // (c100, c101)
            const __half2 h11 = ls[idx + D2 + D];   // (c110, c111)

            // b-lerp with f32 accumulate, then g- and r-lerp in f32.
            const float wb0 = 1.0f - fb;
            const float c00 = __low2float(h00) * wb0 + __high2float(h00) * fb;
            const float c01 = __low2float(h01) * wb0 + __high2float(h01) * fb;
            const float c10 = __low2float(h10) * wb0 + __high2float(h10) * fb;
            const float c11 = __low2float(h11) * wb0 + __high2float(h11) * fb;

            const float c0 = c00 + fg * (c01 - c00);
            const float c1 = c10 + fg * (c11 - c10);
            oo[j] = c0 + fr * (c1 - c0);
        }

        float* ob = out + (size_t)b * 3 * HW + (size_t)c * HW + p;
        *(float4*)ob = make_float4(oo[0], oo[1], oo[2], oo[3]);
    }
}

extern "C" void kernel_launch(void* const* d_in, const int* in_sizes, int n_in,
                              void* d_out, int out_size, void* d_ws, size_t ws_size,
                              hipStream_t stream) {
    const float* lut = (const float*)d_in[0];   // [1,3,33,33,33]
    const float* x   = (const float*)d_in[1];   // [8,3,1024,1024]
    float* out = (float*)d_out;                 // [8,3,1024,1024]

    dim3 grid(3 * CHUNKS);
    lut3d_kernel<<<grid, THREADS, 0, stream>>>(lut, x, out);
}

// Round 4
// 221.150 us; speedup vs baseline: 1.0018x; 1.0018x over previous
//
#include <hip/hip_runtime.h>
#include <hip/hip_fp16.h>

// Trilinear 3D-LUT apply: lut [1,3,33,33,33] f32, x [8,3,1024,1024] f32 in [0,1)
// out [8,3,1024,1024] f32.
//
// V3b (compile fix of V3): fp16 b-pair LDS (4 random LDS addresses/pixel,
//     2x ds_read2_b32) + v_dot2_f32_f16 for the b-lerp (1 instr per
//     corner-pair, f32 accumulate) + baseline grid mapping + non-temporal
//     output stores.
//
// Cost model per pixel: ~26 VALU ops, 4 random-bank LDS addresses (2 instrs).
// Floors: HBM (152 MB fetch + 99 MB write)/6.3 TB/s ~= 40 us; LDS ~27 us;
// VALU ~20 us. Target dispatch ~60-72 us.

#define D   33
#define D2  (33 * 33)
#define D3  (33 * 33 * 33)      // 35937
#define NP  (D3 - 1)            // packed pair entries: 35936 * 4 B = 143,744 B LDS
#define HW  (1024 * 1024)
#define BATCH 8
#define QHW (HW / 4)            // float4 groups per plane
#define NG  (BATCH * QHW)       // float4 groups per channel = 2,097,152
#define CHUNKS 256
#define GPC (NG / CHUNKS)       // groups per chunk = 8192
#define THREADS 1024

typedef __fp16 h16;
typedef __attribute__((ext_vector_type(2))) __fp16 h16x2;   // matches builtin types
typedef __attribute__((ext_vector_type(4))) float f32x4;    // plain vec for nt-store

#if __has_builtin(__builtin_amdgcn_fdot2)
#define DOT2(a, b) __builtin_amdgcn_fdot2((a), (b), 0.0f, false)
#else
static __device__ __forceinline__ float dot2_asm(h16x2 a, h16x2 b) {
    float d;
    asm("v_dot2_f32_f16 %0, %1, %2, 0" : "=v"(d) : "v"(a), "v"(b));
    return d;
}
#define DOT2(a, b) dot2_asm((a), (b))
#endif

__global__ __launch_bounds__(THREADS) void lut3d_kernel(
    const float* __restrict__ lut, const float* __restrict__ x,
    float* __restrict__ out)
{
    const int c     = blockIdx.x;   // output channel 0..2 (fastest dispatch dim:
    const int chunk = blockIdx.y;   // channel-triple of a chunk is temporally
                                    // adjacent -> x reads shared via L2/L3)

    // --- stage one channel cube as fp16 b-pairs: ls[i] = (lut[i], lut[i+1]) ---
    __shared__ h16x2 ls[NP];
    {
        const float* lc = lut + c * D3;
        for (int i = threadIdx.x; i < NP; i += THREADS) {
            h16x2 v;
            v.x = (h16)lc[i];       // float -> __fp16 (RNE)
            v.y = (h16)lc[i + 1];
            ls[i] = v;
        }
    }
    __syncthreads();

    const int tid  = threadIdx.x;
    const int base = chunk * GPC;

    #pragma unroll 1
    for (int it = 0; it < GPC / THREADS; ++it) {
        const int g = base + it * THREADS + tid;       // float4-group id
        const int b = g >> 18;                         // g / QHW (QHW = 2^18)
        const int p = (g & (QHW - 1)) * 4;             // pixel offset in plane

        const float* xb = x + (size_t)b * 3 * HW + p;
        const float4 xr = *(const float4*)(xb);
        const float4 xg = *(const float4*)(xb + HW);
        const float4 xB = *(const float4*)(xb + 2 * HW);

        const float rr[4] = {xr.x, xr.y, xr.z, xr.w};
        const float gg[4] = {xg.x, xg.y, xg.z, xg.w};
        const float bb[4] = {xB.x, xB.y, xB.z, xB.w};
        float oo[4];

        #pragma unroll
        for (int j = 0; j < 4; ++j) {
            // clamp(x,0,1)*32, capped below 32 so i0<=31 always: neighbor
            // offsets +1/+33/+1089 become compile-time constants.
            const float vr = fminf(fmaxf(rr[j], 0.f) * 32.f, 31.999998f);
            const float vg = fminf(fmaxf(gg[j], 0.f) * 32.f, 31.999998f);
            const float vb = fminf(fmaxf(bb[j], 0.f) * 32.f, 31.999998f);

            const int r0 = (int)vr, g0 = (int)vg, b0 = (int)vb;  // trunc==floor
            const float fr = vr - (float)r0;
            const float fg = vg - (float)g0;
            const float fb = vb - (float)b0;

            const int idx = r0 * D2 + g0 * D + b0;

            // 4 dwords at const dword offsets {0, 33, 1089, 1122} from one
            // base -> 2x ds_read2_b32 (offsets 0/33 from bases idx, idx+1089).
            const h16x2 h00 = ls[idx];            // (c000, c001)
            const h16x2 h01 = ls[idx + D];        // (c010, c011)
            const h16x2 h10 = ls[idx + D2];       // (c100, c101)
            const h16x2 h11 = ls[idx + D2 + D];   // (c110, c111)

            // b-lerp: one v_dot2_f32_f16 per corner-pair, f32 accumulate.
            const h16x2 w = __builtin_amdgcn_cvt_pkrtz(1.0f - fb, fb);
            const float c00 = DOT2(h00, w);
            const float c01 = DOT2(h01, w);
            const float c10 = DOT2(h10, w);
            const float c11 = DOT2(h11, w);

            const float c0 = c00 + fg * (c01 - c00);
            const float c1 = c10 + fg * (c11 - c10);
            oo[j] = c0 + fr * (c1 - c0);
        }

        float* ob = out + (size_t)b * 3 * HW + (size_t)c * HW + p;
        // write-once data: non-temporal store keeps L2 for x-sharing lines
        f32x4 ov;
        ov.x = oo[0]; ov.y = oo[1]; ov.z = oo[2]; ov.w = oo[3];
        __builtin_nontemporal_store(ov, (f32x4*)ob);
    }
}

extern "C" void kernel_launch(void* const* d_in, const int* in_sizes, int n_in,
                              void* d_out, int out_size, void* d_ws, size_t ws_size,
                              hipStream_t stream) {
    const float* lut = (const float*)d_in[0];   // [1,3,33,33,33]
    const float* x   = (const float*)d_in[1];   // [8,3,1024,1024]
    float* out = (float*)d_out;                 // [8,3,1024,1024]

    dim3 grid(3, CHUNKS);
    lut3d_kernel<<<grid, THREADS, 0, stream>>>(lut, x, out);
}